// Round 13
// baseline (183.140 us; speedup 1.0000x reference)
//
#include <hip/hip_runtime.h>
#include <stdint.h>

typedef unsigned short u16;
typedef unsigned int   u32;

#define EPSF  1e-7f
#define MINN  1e-15f

// problem constants: n=8192, t=16, d=64
#define CPR  524288      // elements per big row (n*d)
#define NE   136         // number of (m,nn) pairs
#define QS   68          // qv/kv row stride (floats)
#define VS   68          // vrow row stride (padded)
#define CMS  17          // Cm row stride (padded)
#define NBANK 7          // Gram atomic banks

// ws layout (floats): [0 .. NBANK*136) banked G partials, then fin outputs:
#define WQP 952
#define WKP 1208
#define SCQ 1464
#define SCK 1480
#define CHQ 1496
#define CHK 1512
#define UQ  1528
#define UK  1592
// end 1656 floats

__device__ __forceinline__ float bf2f(u16 u){ u32 x = ((u32)u)<<16; return __uint_as_float(x); }
__device__ __forceinline__ float ldv(const void* p, size_t i, int f32m){
    return f32m ? ((const float*)p)[i] : bf2f(((const u16*)p)[i]);
}
__device__ __forceinline__ float arcosh_f(float x){
    return logf(x + sqrtf(fmaxf(x*x - 1.0f, EPSF)));
}
__device__ __forceinline__ float clampf(float v, float lim){
    return fmaxf(fminf(v, lim), -lim);
}
__device__ __forceinline__ float red16(float v){
    v += __shfl_xor(v,1); v += __shfl_xor(v,2);
    v += __shfl_xor(v,4); v += __shfl_xor(v,8);
    return v;
}
__device__ __forceinline__ int detect_f32(const void* Hv){
    const float* Hf = (const float*)Hv;
    int ok = 1;
#pragma unroll
    for(int i=0;i<16;i++){
        float v = Hf[(size_t)i*1024];
        if(!(v > 0.9f && v < 1000.f)) ok = 0;
    }
    return ok;
}

__device__ __forceinline__ void load_tile(const void* Hv, int f32m, int i0, int c0, float4* hx){
    if(f32m){
        const float* Hf = (const float*)Hv;
#pragma unroll
        for(int s=0;s<16;s++) hx[s] = *(const float4*)(Hf + ((size_t)(512*s + i0))*1024 + c0);
    } else {
        const u16* Hu = (const u16*)Hv;
#pragma unroll
        for(int s=0;s<16;s++){
            ushort4 u4 = *(const ushort4*)(Hu + ((size_t)(512*s + i0))*1024 + c0);
            hx[s] = make_float4(bf2f(u4.x), bf2f(u4.y), bf2f(u4.z), bf2f(u4.w));
        }
    }
}

// ---------------------------------------------------------------------------
// Kernel 1: Gram. Grid 512, one H read, LDS scatter-reduce (unchanged, R12).
// ---------------------------------------------------------------------------
template<int G>
__device__ __forceinline__ void gram_body(const float4* hx, float* acc){
    int p=0;
#pragma unroll
    for(int s=0;s<16;s++){
#pragma unroll
        for(int s2=s;s2<16;s2++){
            if(p >= 34*G && p < 34*G+34){
                acc[p-34*G] = hx[s].x*hx[s2].x + hx[s].y*hx[s2].y
                            + hx[s].z*hx[s2].z + hx[s].w*hx[s2].w;
            }
            p++;
        }
    }
}

__global__ __launch_bounds__(256) void gram4_k(const void* __restrict__ Hv, float* __restrict__ ws){
    __shared__ float red[256*35];       // [t][j], stride 35 -> bank-clean
    const int tid = threadIdx.x;
    const int i0  = blockIdx.x;         // column slice 0..511
    const int f32m = detect_f32(Hv);
    const int c0 = tid*4;

    float4 hx[16];
    load_tile(Hv, f32m, i0, c0, hx);

#define GRAM_GROUP(G) { \
        float acc[34]; \
        gram_body<G>(hx, acc); \
        _Pragma("unroll") \
        for(int j=0;j<34;j++) red[tid*35+j] = acc[j]; \
        __syncthreads(); \
        if(tid < 136){ \
            int j = tid>>2, q = tid&3; \
            float s = 0.f; \
            _Pragma("unroll 16") \
            for(int t=q*64; t<q*64+64; t++) s += red[t*35 + j]; \
            s += __shfl_xor(s,1); s += __shfl_xor(s,2); \
            if(q==0) atomicAdd(&ws[(i0%NBANK)*NE + 34*G + j], s); \
        } \
        __syncthreads(); }

    GRAM_GROUP(0)
    GRAM_GROUP(1)
    GRAM_GROUP(2)
    GRAM_GROUP(3)
#undef GRAM_GROUP
}

// ---------------------------------------------------------------------------
// Kernel 2: finalize scalars (1 block, 256 threads) — unchanged from R10-R12.
// ---------------------------------------------------------------------------
__global__ void fin4_k(const void* __restrict__ Hv, const void* __restrict__ wq, const void* __restrict__ wk,
                       const void* __restrict__ bq, const void* __restrict__ bk, const void* __restrict__ cc,
                       float* __restrict__ ws){
    __shared__ float Gy[16][17], alpha[16], h0s[16], wqp[256], wkp[256], aus[2];
    const int tid = threadIdx.x;
    const int row = tid>>4, l = tid&15;
    const int f32m = detect_f32(Hv);
    float cv = fmaxf(ldv(cc,0,f32m), 1e-20f);
    float K = 1.f/cv, sqK = sqrtf(K);
    if(tid<16) h0s[tid] = ldv(Hv, (size_t)tid*CPR, f32m);
    __syncthreads();
    if(tid<NE){
        int s=0, rem=tid;
        while(rem >= 16 - s){ rem -= 16 - s; s++; }
        int s2 = s + rem;
        float gsum = 0.f;
#pragma unroll
        for(int b=0;b<NBANK;b++) gsum += ws[b*NE+tid];
        float g = gsum - h0s[s]*h0s[s2];
        Gy[s][s2] = g; Gy[s2][s] = g;
    }
    __syncthreads();
    if(tid<16){
        float ny = fmaxf(sqrtf(fmaxf(Gy[tid][tid],0.f)), MINN);
        float th = fmaxf(h0s[tid]/sqK, 1.0f+EPSF);
        alpha[tid] = sqK*arcosh_f(th)/ny;
    }
    __syncthreads();
    {
        float aq = ldv(wq,tid,f32m)*alpha[l];
        float ak = ldv(wk,tid,f32m)*alpha[l];
        wqp[tid] = aq; wkp[tid] = ak;
        ws[WQP+tid] = aq; ws[WKP+tid] = ak;
    }
    if(tid<128){
        int lane = tid&63;
        const void* bb = (tid<64)? bq : bk;
        float v = (lane==0)? 0.f : ldv(bb,lane,f32m);
        float sn = v*v;
        sn += __shfl_xor(sn,1);  sn += __shfl_xor(sn,2);  sn += __shfl_xor(sn,4);
        sn += __shfl_xor(sn,8);  sn += __shfl_xor(sn,16); sn += __shfl_xor(sn,32);
        if(lane==0){
            float b0 = ldv(bb,0,f32m);
            float nb = fmaxf(sqrtf(sn), MINN);
            float th = fmaxf(b0/sqK, 1.0f+EPSF);
            aus[tid>>6] = sqK*arcosh_f(th)/nb;
        }
    }
    __syncthreads();
    {
        float innerQ = 0.f, innerK = 0.f;
#pragma unroll
        for(int s2=0;s2<16;s2++){
            float gy = Gy[l][s2];
            innerQ += wqp[row*16+s2]*gy;
            innerK += wkp[row*16+s2]*gy;
        }
        float tq = red16(wqp[row*16+l]*innerQ);
        float tk = red16(wkp[row*16+l]*innerK);
        if(l==0){
            float xn = fmaxf(sqrtf(fmaxf(tq,0.f)), MINN);
            float thc = fminf(xn/sqK, 80.f);
            ws[SCQ+row] = clampf(sqK*sinhf(thc)/xn, 1e18f);
            ws[CHQ+row] = clampf(sqK*coshf(thc),    1e18f);
            xn = fmaxf(sqrtf(fmaxf(tk,0.f)), MINN);
            thc = fminf(xn/sqK, 80.f);
            ws[SCK+row] = clampf(sqK*sinhf(thc)/xn, 1e18f);
            ws[CHK+row] = clampf(sqK*coshf(thc),    1e18f);
        }
    }
    if(tid<64){
        ws[UQ+tid] = (tid==0)?0.f : clampf(aus[0]*ldv(bq,tid,f32m), 1e18f);
        ws[UK+tid] = (tid==0)?0.f : clampf(aus[1]*ldv(bk,tid,f32m), 1e18f);
    }
}

// ---------------------------------------------------------------------------
// Kernel 3: transform + attention. Grid 8192, 1 r per block, streaming
// A-phase (R11 structure). R13 changes, both targeting the measured
// VALU-issue bound (86.5us @ 85% VALUBusy, 66% occ):
//  (1) __launch_bounds__(256,8): 8 blocks/CU (LDS 8x18.9K=151K<160K; VGPR
//      cap 64 >= 36 used, no spill risk) -> 32 waves/CU vs 24.
//  (2) fast VALU ops: IEEE div (~12 insts) -> __fdividef/rsqrtf (~3);
//      mdot/K -> -mdot*cv; C2 logf/expf -> __logf/__expf. coshf/sinhf
//      KEPT (exp-based recombination cancels at small theta). Error
//      ~1e-6 rel << bf16-input-dominated tolerance; absmax is tripwire.
// ---------------------------------------------------------------------------
__global__ __launch_bounds__(256,8) void main8_k(const void* __restrict__ Hv, const int* __restrict__ tidx,
        const void* __restrict__ mask, const void* __restrict__ aav, const void* __restrict__ ccv,
        const float* __restrict__ ws, float* __restrict__ out){
    __shared__ __attribute__((aligned(16))) float vrow[16*VS];
    __shared__ __attribute__((aligned(16))) float qv[16*QS];
    __shared__ __attribute__((aligned(16))) float kv[16*QS];
    __shared__ float wqp[256], wkp[256], scQ[16], scK[16], chQ[16], chK[16], uq[64], uk[64];
    __shared__ float ssum[16], Cm[16*CMS], lamb[16], invv[16];
    __shared__ int   tmv[NE], tnv[NE];
    __shared__ float maskv[NE];

    const int tid = threadIdx.x;
    const int r   = blockIdx.x >> 9;     // 0..15
    const int i0  = blockIdx.x & 511;    // column slice
    const int row = tid>>4, l = tid&15;
    const int f32m = detect_f32(Hv);
    const float av = ldv(aav,0,f32m);
    const float cv = fmaxf(ldv(ccv,0,f32m), 1e-20f);
    const float K = 1.f/cv, sqK = sqrtf(K);
    const int i64m = (tidx[1] != 1);
    const int c0 = tid*4;

    const float* Hf = (const float*)Hv;
    const u16*   Hu = (const u16*)Hv;

    // ---- prelude: pure loads of fin4_k output ----
    wqp[tid] = ws[WQP+tid]; wkp[tid] = ws[WKP+tid];
    if(tid<16){ scQ[tid]=ws[SCQ+tid]; scK[tid]=ws[SCK+tid]; chQ[tid]=ws[CHQ+tid]; chK[tid]=ws[CHK+tid]; }
    if(tid<64){ uq[tid]=ws[UQ+tid]; uk[tid]=ws[UK+tid]; }
    if(tid<NE){
        if(i64m){ tmv[tid]=tidx[2*tid]&15; tnv[tid]=tidx[2*NE+2*tid]&15; }
        else    { tmv[tid]=tidx[tid]&15;   tnv[tid]=tidx[NE+tid]&15; }
        maskv[tid]=ldv(mask,tid,f32m);
    }
    __syncthreads();

    // ---- streaming A-phase: load row, FMA, discard; capture v-row at J=0 ---
    float aq0=0,aq1=0,aq2=0,aq3=0, ak0=0,ak1=0,ak2=0,ak3=0;
    float4 vr;
    const int rQ = r<<4;
    if(f32m){
#define STEPF(J) { const int s_=(r+J)&15; \
        float4 b = *(const float4*)(Hf + ((size_t)(512*s_ + i0))*1024 + c0); \
        if(J==0) vr = b; \
        float wq_=wqp[rQ+s_], wk_=wkp[rQ+s_]; \
        aq0 += wq_*b.x; aq1 += wq_*b.y; aq2 += wq_*b.z; aq3 += wq_*b.w; \
        ak0 += wk_*b.x; ak1 += wk_*b.y; ak2 += wk_*b.z; ak3 += wk_*b.w; }
        STEPF(0)  STEPF(1)  STEPF(2)  STEPF(3)
        STEPF(4)  STEPF(5)  STEPF(6)  STEPF(7)
        STEPF(8)  STEPF(9)  STEPF(10) STEPF(11)
        STEPF(12) STEPF(13) STEPF(14) STEPF(15)
#undef STEPF
    } else {
#define STEPB(J) { const int s_=(r+J)&15; \
        ushort4 u4_ = *(const ushort4*)(Hu + ((size_t)(512*s_ + i0))*1024 + c0); \
        float4 b = make_float4(bf2f(u4_.x), bf2f(u4_.y), bf2f(u4_.z), bf2f(u4_.w)); \
        if(J==0) vr = b; \
        float wq_=wqp[rQ+s_], wk_=wkp[rQ+s_]; \
        aq0 += wq_*b.x; aq1 += wq_*b.y; aq2 += wq_*b.z; aq3 += wq_*b.w; \
        ak0 += wk_*b.x; ak1 += wk_*b.y; ak2 += wk_*b.z; ak3 += wk_*b.w; }
        STEPB(0)  STEPB(1)  STEPB(2)  STEPB(3)
        STEPB(4)  STEPB(5)  STEPB(6)  STEPB(7)
        STEPB(8)  STEPB(9)  STEPB(10) STEPB(11)
        STEPB(12) STEPB(13) STEPB(14) STEPB(15)
#undef STEPB
    }

    // --- A epilogue: scale + store to qv/kv ---
    {
        float sq_ = scQ[r], sk_ = scK[r];
        float q0 = clampf(sq_*aq0,1e18f), q1=clampf(sq_*aq1,1e18f),
              q2 = clampf(sq_*aq2,1e18f), q3=clampf(sq_*aq3,1e18f);
        float k0 = clampf(sk_*ak0,1e18f), k1=clampf(sk_*ak1,1e18f),
              k2 = clampf(sk_*ak2,1e18f), k3=clampf(sk_*ak3,1e18f);
        if(i0==0 && tid==0){ q0 = chQ[r]; k0 = chK[r]; }
        *(float4*)(qv + row*QS + l*4) = make_float4(q0,q1,q2,q3);
        *(float4*)(kv + row*QS + l*4) = make_float4(k0,k1,k2,k3);
    }

    // --- C1: v row = vr (pure register) ---
    {
        *(float4*)(vrow + row*VS + l*4) = vr;
        float x0v = vrow[row*VS];
        float inv0 = __fdividef(1.f, ((fabsf(x0v)>1e-20f)? x0v : 1e-20f));
        float sv = 0.f;
#pragma unroll
        for(int m=0;m<4;m++){
            int kp = l + 16*m;
            if(kp < 63){ float vi = vrow[row*VS + 1 + kp]*inv0; sv += vi*vi; }
        }
        sv = red16(sv);
        if(l==0){ lamb[row] = rsqrtf(1.f - fminf(sv, 0.9f)); invv[row] = inv0; }
        if(tid<16) ssum[tid]=0.f;
        Cm[tid]=0.f;
        if(tid<16) Cm[256+tid]=0.f;
    }

    // --- M: mobius_add(+proj) on q and k rows, in-wave ---
    {
        float xq[4], xk[4];
        float syq=0,suq=0,syk=0,suk=0;
#pragma unroll
        for(int m=0;m<4;m++){
            int k = l+16*m;
            xq[m]=qv[row*QS+k]; xk[m]=kv[row*QS+k];
            if(k>0){ syq+=xq[m]*xq[m]; suq+=xq[m]*uq[k];
                     syk+=xk[m]*xk[m]; suk+=xk[m]*uk[k]; }
        }
        syq=red16(syq); suq=red16(suq); syk=red16(syk); suk=red16(suk);
        float x0q=qv[row*QS], x0k=kv[row*QS];
        float xnq=fmaxf(sqrtf(fmaxf(syq,0.f)),MINN);
        float xnk=fmaxf(sqrtf(fmaxf(syk,0.f)),MINN);
        float alq=clampf(__fdividef(suq, xnq*sqK),1e12f);
        float alk=clampf(__fdividef(suk, xnk*sqK),1e12f);
        float cfq=clampf(__fdividef(alq*(sqK-x0q), xnq),1e12f);
        float cfk=clampf(__fdividef(alk*(sqK-x0k), xnk),1e12f);
        float wq4[4], wk4[4];
        float uxq=0,swq=0,uxk=0,swk=0;
#pragma unroll
        for(int m=0;m<4;m++){
            int k=l+16*m;
            if(k>0){
                wq4[m]=clampf(uq[k]-cfq*xq[m],1e15f); uxq+=xq[m]*wq4[m]; swq+=wq4[m]*wq4[m];
                wk4[m]=clampf(uk[k]-cfk*xk[m],1e15f); uxk+=xk[m]*wk4[m]; swk+=wk4[m]*wk4[m];
            } else { wq4[m]=0.f; wk4[m]=0.f; }
        }
        uxq=red16(uxq); swq=red16(swq); uxk=red16(uxk); swk=red16(swk);
        float V0q=__fdividef(uxq, fmaxf(x0q,EPSF));
        float V0k=__fdividef(uxk, fmaxf(x0k,EPSF));
        float mnq=sqrtf(fmaxf(swq-V0q*V0q,EPSF));
        float mnk=sqrtf(fmaxf(swk-V0k*V0k,EPSF));
        float thq=fminf(fmaxf(fminf(mnq,1e6f)/sqK,MINN),20.f);
        float thk=fminf(fmaxf(fminf(mnk,1e6f)/sqK,MINN),20.f);
        float chq=coshf(thq), stq=__fdividef(sinhf(thq), thq);
        float chk=coshf(thk), stk=__fdividef(sinhf(thk), thk);
        float zq4[4], zk4[4];
        float szq=0,szk=0;
#pragma unroll
        for(int m=0;m<4;m++){
            int k=l+16*m;
            if(k>0){
                zq4[m]=clampf(chq*xq[m]+stq*wq4[m],1e15f); szq+=zq4[m]*zq4[m];
                zk4[m]=clampf(chk*xk[m]+stk*wk4[m],1e15f); szk+=zk4[m]*zk4[m];
            } else { zq4[m]=0.f; zk4[m]=0.f; }
        }
        szq=red16(szq); szk=red16(szk);
        float fq = sqrtf(fmaxf(K+szq,EPSF));
        float fk = sqrtf(fmaxf(K+szk,EPSF));
#pragma unroll
        for(int m=0;m<4;m++){
            int k=l+16*m;
            qv[row*QS+k] = (k==0)? fq : zq4[m];
            kv[row*QS+k] = (k==0)? fk : zk4[m];
        }
    }
    __syncthreads();

    // --- C2: scores; scatter s_sum ---
    if(tid<NE){
        int m = tmv[tid], nn = tnv[tid];
        const float4* qp = (const float4*)(qv + m*QS);
        const float4* kp = (const float4*)(kv + nn*QS);
        float dot = 0.f;
#pragma unroll
        for(int t4=0;t4<16;t4++){
            float4 q4 = qp[t4], k4 = kp[t4];
            dot += q4.x*k4.x + q4.y*k4.y + q4.z*k4.z + q4.w*k4.w;
        }
        float mdot = dot - 2.f*qv[m*QS]*kv[nn*QS];
        float th = fmaxf(-mdot*cv, 1.0f+EPSF);
        float ac = __logf(th + sqrtf(fmaxf(th*th - 1.0f, EPSF)));
        float sqd = fminf(K*ac*ac, 50.f);
        float sval = __expf(fminf(-av*sqd - cv + maskv[tid], 80.f));
        Cm[m*CMS+nn] = sval;
        atomicAdd(&ssum[m], sval);
    }
    __syncthreads();

    // --- C3: scale ---
    if(tid<NE){
        int m = tmv[tid], nn = tnv[tid];
        Cm[m*CMS+nn] = __fdividef(lamb[nn]*Cm[m*CMS+nn], fmaxf(ssum[nn],1e-37f));
    }
    __syncthreads();

    // --- D: weighted Klein average + k2h ---
    {
        float cs[16]; float wsm = 0.f;
#pragma unroll
        for(int s=0;s<16;s++){
            float cmv = Cm[row*CMS+s];
            wsm += cmv;
            cs[s] = cmv*invv[s];
        }
        wsm = fmaxf(wsm, 1e-37f);
        float iwsm = __fdividef(1.f, wsm);
        float g4[4]; float sg=0.f;
#pragma unroll
        for(int m=0;m<4;m++){
            int kp = l+16*m;
            float num = 0.f;
#pragma unroll
            for(int s=0;s<16;s++) num += cs[s]*vrow[s*VS + 1 + kp];
            float gvv = (kp<63)? num*iwsm : 0.f;
            g4[m]=gvv; sg += gvv*gvv;
        }
        sg = red16(sg);
        float inv = rsqrtf(1.f - fminf(sg, 0.999f));
        size_t base = ((size_t)(512*r + i0)*16 + row)*64;
        if(l==0) out[base] = inv;
#pragma unroll
        for(int m=0;m<4;m++){
            int kp=l+16*m;
            if(kp<63) out[base+1+kp] = g4[m]*inv;
        }
    }
}

extern "C" void kernel_launch(void* const* d_in, const int* in_sizes, int n_in,
                              void* d_out, int out_size, void* d_ws, size_t ws_size,
                              hipStream_t stream){
    const void* H    = d_in[0];
    const int* tidx  = (const int*)d_in[1];
    const void* mask = d_in[2];
    const void* wq   = d_in[3];
    const void* wk   = d_in[4];
    const void* bq   = d_in[5];
    const void* bk   = d_in[6];
    const void* aa   = d_in[7];
    const void* cc   = d_in[8];
    float* out = (float*)d_out;
    float* ws  = (float*)d_ws;

    hipMemsetAsync(ws, 0, NBANK*NE*sizeof(float), stream);
    gram4_k<<<512, 256,0,stream>>>(H, ws);
    fin4_k <<<1,   256,0,stream>>>(H, wq, wk, bq, bk, cc, ws);
    main8_k<<<8192,256,0,stream>>>(H, tidx, mask, aa, cc, ws, out);
}

// Round 14
// 174.998 us; speedup vs baseline: 1.0465x; 1.0465x over previous
//
#include <hip/hip_runtime.h>
#include <stdint.h>

typedef unsigned short u16;
typedef unsigned int   u32;

#define EPSF  1e-7f
#define MINN  1e-15f

// problem constants: n=8192, t=16, d=64
#define CPR  524288      // elements per big row (n*d)
#define NE   136         // number of (m,nn) pairs
#define QS   68          // qv/kv row stride (floats)
#define VS   68          // vrow row stride (padded)
#define CMS  17          // Cm row stride (padded)
#define NBANK 7          // Gram atomic banks

// ws layout (floats): [0 .. NBANK*136) banked G partials, then fin outputs:
#define WQP 952
#define WKP 1208
#define SCQ 1464
#define SCK 1480
#define CHQ 1496
#define CHK 1512
#define UQ  1528
#define UK  1592
// end 1656 floats

__device__ __forceinline__ float bf2f(u16 u){ u32 x = ((u32)u)<<16; return __uint_as_float(x); }
__device__ __forceinline__ float ldv(const void* p, size_t i, int f32m){
    return f32m ? ((const float*)p)[i] : bf2f(((const u16*)p)[i]);
}
__device__ __forceinline__ float arcosh_f(float x){
    return logf(x + sqrtf(fmaxf(x*x - 1.0f, EPSF)));
}
__device__ __forceinline__ float clampf(float v, float lim){
    return fmaxf(fminf(v, lim), -lim);
}
__device__ __forceinline__ float red16(float v){
    v += __shfl_xor(v,1); v += __shfl_xor(v,2);
    v += __shfl_xor(v,4); v += __shfl_xor(v,8);
    return v;
}
__device__ __forceinline__ int detect_f32(const void* Hv){
    const float* Hf = (const float*)Hv;
    int ok = 1;
#pragma unroll
    for(int i=0;i<16;i++){
        float v = Hf[(size_t)i*1024];
        if(!(v > 0.9f && v < 1000.f)) ok = 0;
    }
    return ok;
}

__device__ __forceinline__ void load_tile(const void* Hv, int f32m, int i0, int c0, float4* hx){
    if(f32m){
        const float* Hf = (const float*)Hv;
#pragma unroll
        for(int s=0;s<16;s++) hx[s] = *(const float4*)(Hf + ((size_t)(512*s + i0))*1024 + c0);
    } else {
        const u16* Hu = (const u16*)Hv;
#pragma unroll
        for(int s=0;s<16;s++){
            ushort4 u4 = *(const ushort4*)(Hu + ((size_t)(512*s + i0))*1024 + c0);
            hx[s] = make_float4(bf2f(u4.x), bf2f(u4.y), bf2f(u4.z), bf2f(u4.w));
        }
    }
}

// ---------------------------------------------------------------------------
// Kernel 1: Gram. Grid 512, one H read, LDS scatter-reduce (unchanged, R12).
// ---------------------------------------------------------------------------
template<int G>
__device__ __forceinline__ void gram_body(const float4* hx, float* acc){
    int p=0;
#pragma unroll
    for(int s=0;s<16;s++){
#pragma unroll
        for(int s2=s;s2<16;s2++){
            if(p >= 34*G && p < 34*G+34){
                acc[p-34*G] = hx[s].x*hx[s2].x + hx[s].y*hx[s2].y
                            + hx[s].z*hx[s2].z + hx[s].w*hx[s2].w;
            }
            p++;
        }
    }
}

__global__ __launch_bounds__(256) void gram4_k(const void* __restrict__ Hv, float* __restrict__ ws){
    __shared__ float red[256*35];       // [t][j], stride 35 -> bank-clean
    const int tid = threadIdx.x;
    const int i0  = blockIdx.x;         // column slice 0..511
    const int f32m = detect_f32(Hv);
    const int c0 = tid*4;

    float4 hx[16];
    load_tile(Hv, f32m, i0, c0, hx);

#define GRAM_GROUP(G) { \
        float acc[34]; \
        gram_body<G>(hx, acc); \
        _Pragma("unroll") \
        for(int j=0;j<34;j++) red[tid*35+j] = acc[j]; \
        __syncthreads(); \
        if(tid < 136){ \
            int j = tid>>2, q = tid&3; \
            float s = 0.f; \
            _Pragma("unroll 16") \
            for(int t=q*64; t<q*64+64; t++) s += red[t*35 + j]; \
            s += __shfl_xor(s,1); s += __shfl_xor(s,2); \
            if(q==0) atomicAdd(&ws[(i0%NBANK)*NE + 34*G + j], s); \
        } \
        __syncthreads(); }

    GRAM_GROUP(0)
    GRAM_GROUP(1)
    GRAM_GROUP(2)
    GRAM_GROUP(3)
#undef GRAM_GROUP
}

// ---------------------------------------------------------------------------
// Kernel 2: finalize scalars (1 block, 256 threads) — unchanged from R10-R13.
// ---------------------------------------------------------------------------
__global__ void fin4_k(const void* __restrict__ Hv, const void* __restrict__ wq, const void* __restrict__ wk,
                       const void* __restrict__ bq, const void* __restrict__ bk, const void* __restrict__ cc,
                       float* __restrict__ ws){
    __shared__ float Gy[16][17], alpha[16], h0s[16], wqp[256], wkp[256], aus[2];
    const int tid = threadIdx.x;
    const int row = tid>>4, l = tid&15;
    const int f32m = detect_f32(Hv);
    float cv = fmaxf(ldv(cc,0,f32m), 1e-20f);
    float K = 1.f/cv, sqK = sqrtf(K);
    if(tid<16) h0s[tid] = ldv(Hv, (size_t)tid*CPR, f32m);
    __syncthreads();
    if(tid<NE){
        int s=0, rem=tid;
        while(rem >= 16 - s){ rem -= 16 - s; s++; }
        int s2 = s + rem;
        float gsum = 0.f;
#pragma unroll
        for(int b=0;b<NBANK;b++) gsum += ws[b*NE+tid];
        float g = gsum - h0s[s]*h0s[s2];
        Gy[s][s2] = g; Gy[s2][s] = g;
    }
    __syncthreads();
    if(tid<16){
        float ny = fmaxf(sqrtf(fmaxf(Gy[tid][tid],0.f)), MINN);
        float th = fmaxf(h0s[tid]/sqK, 1.0f+EPSF);
        alpha[tid] = sqK*arcosh_f(th)/ny;
    }
    __syncthreads();
    {
        float aq = ldv(wq,tid,f32m)*alpha[l];
        float ak = ldv(wk,tid,f32m)*alpha[l];
        wqp[tid] = aq; wkp[tid] = ak;
        ws[WQP+tid] = aq; ws[WKP+tid] = ak;
    }
    if(tid<128){
        int lane = tid&63;
        const void* bb = (tid<64)? bq : bk;
        float v = (lane==0)? 0.f : ldv(bb,lane,f32m);
        float sn = v*v;
        sn += __shfl_xor(sn,1);  sn += __shfl_xor(sn,2);  sn += __shfl_xor(sn,4);
        sn += __shfl_xor(sn,8);  sn += __shfl_xor(sn,16); sn += __shfl_xor(sn,32);
        if(lane==0){
            float b0 = ldv(bb,0,f32m);
            float nb = fmaxf(sqrtf(sn), MINN);
            float th = fmaxf(b0/sqK, 1.0f+EPSF);
            aus[tid>>6] = sqK*arcosh_f(th)/nb;
        }
    }
    __syncthreads();
    {
        float innerQ = 0.f, innerK = 0.f;
#pragma unroll
        for(int s2=0;s2<16;s2++){
            float gy = Gy[l][s2];
            innerQ += wqp[row*16+s2]*gy;
            innerK += wkp[row*16+s2]*gy;
        }
        float tq = red16(wqp[row*16+l]*innerQ);
        float tk = red16(wkp[row*16+l]*innerK);
        if(l==0){
            float xn = fmaxf(sqrtf(fmaxf(tq,0.f)), MINN);
            float thc = fminf(xn/sqK, 80.f);
            ws[SCQ+row] = clampf(sqK*sinhf(thc)/xn, 1e18f);
            ws[CHQ+row] = clampf(sqK*coshf(thc),    1e18f);
            xn = fmaxf(sqrtf(fmaxf(tk,0.f)), MINN);
            thc = fminf(xn/sqK, 80.f);
            ws[SCK+row] = clampf(sqK*sinhf(thc)/xn, 1e18f);
            ws[CHK+row] = clampf(sqK*coshf(thc),    1e18f);
        }
    }
    if(tid<64){
        ws[UQ+tid] = (tid==0)?0.f : clampf(aus[0]*ldv(bq,tid,f32m), 1e18f);
        ws[UK+tid] = (tid==0)?0.f : clampf(aus[1]*ldv(bk,tid,f32m), 1e18f);
    }
}

// ---------------------------------------------------------------------------
// Kernel 3: transform + attention. Grid 8192, 1 r per block, streaming
// A-phase. R14: fast-math KEPT (fdividef/rsqrtf/__logf/__expf, div->mul),
// occupancy bound REVERTED to (256,6) — R13's (256,8) capped VGPR at 64 and
// induced a ~6-float/thread scratch spill (WRITE_SIZE 32768->82044 KB,
// FETCH +92 MB) that erased the occupancy gain (VALUBusy 85->76).
// Single-variable: this isolates the fast-math delta at the proven 6-wave
// occupancy. Spill tripwire: WRITE_SIZE must be 32768 KB.
// ---------------------------------------------------------------------------
__global__ __launch_bounds__(256,6) void main9_k(const void* __restrict__ Hv, const int* __restrict__ tidx,
        const void* __restrict__ mask, const void* __restrict__ aav, const void* __restrict__ ccv,
        const float* __restrict__ ws, float* __restrict__ out){
    __shared__ __attribute__((aligned(16))) float vrow[16*VS];
    __shared__ __attribute__((aligned(16))) float qv[16*QS];
    __shared__ __attribute__((aligned(16))) float kv[16*QS];
    __shared__ float wqp[256], wkp[256], scQ[16], scK[16], chQ[16], chK[16], uq[64], uk[64];
    __shared__ float ssum[16], Cm[16*CMS], lamb[16], invv[16];
    __shared__ int   tmv[NE], tnv[NE];
    __shared__ float maskv[NE];

    const int tid = threadIdx.x;
    const int r   = blockIdx.x >> 9;     // 0..15
    const int i0  = blockIdx.x & 511;    // column slice
    const int row = tid>>4, l = tid&15;
    const int f32m = detect_f32(Hv);
    const float av = ldv(aav,0,f32m);
    const float cv = fmaxf(ldv(ccv,0,f32m), 1e-20f);
    const float K = 1.f/cv, sqK = sqrtf(K);
    const int i64m = (tidx[1] != 1);
    const int c0 = tid*4;

    const float* Hf = (const float*)Hv;
    const u16*   Hu = (const u16*)Hv;

    // ---- prelude: pure loads of fin4_k output ----
    wqp[tid] = ws[WQP+tid]; wkp[tid] = ws[WKP+tid];
    if(tid<16){ scQ[tid]=ws[SCQ+tid]; scK[tid]=ws[SCK+tid]; chQ[tid]=ws[CHQ+tid]; chK[tid]=ws[CHK+tid]; }
    if(tid<64){ uq[tid]=ws[UQ+tid]; uk[tid]=ws[UK+tid]; }
    if(tid<NE){
        if(i64m){ tmv[tid]=tidx[2*tid]&15; tnv[tid]=tidx[2*NE+2*tid]&15; }
        else    { tmv[tid]=tidx[tid]&15;   tnv[tid]=tidx[NE+tid]&15; }
        maskv[tid]=ldv(mask,tid,f32m);
    }
    __syncthreads();

    // ---- streaming A-phase: load row, FMA, discard; capture v-row at J=0 ---
    float aq0=0,aq1=0,aq2=0,aq3=0, ak0=0,ak1=0,ak2=0,ak3=0;
    float4 vr;
    const int rQ = r<<4;
    if(f32m){
#define STEPF(J) { const int s_=(r+J)&15; \
        float4 b = *(const float4*)(Hf + ((size_t)(512*s_ + i0))*1024 + c0); \
        if(J==0) vr = b; \
        float wq_=wqp[rQ+s_], wk_=wkp[rQ+s_]; \
        aq0 += wq_*b.x; aq1 += wq_*b.y; aq2 += wq_*b.z; aq3 += wq_*b.w; \
        ak0 += wk_*b.x; ak1 += wk_*b.y; ak2 += wk_*b.z; ak3 += wk_*b.w; }
        STEPF(0)  STEPF(1)  STEPF(2)  STEPF(3)
        STEPF(4)  STEPF(5)  STEPF(6)  STEPF(7)
        STEPF(8)  STEPF(9)  STEPF(10) STEPF(11)
        STEPF(12) STEPF(13) STEPF(14) STEPF(15)
#undef STEPF
    } else {
#define STEPB(J) { const int s_=(r+J)&15; \
        ushort4 u4_ = *(const ushort4*)(Hu + ((size_t)(512*s_ + i0))*1024 + c0); \
        float4 b = make_float4(bf2f(u4_.x), bf2f(u4_.y), bf2f(u4_.z), bf2f(u4_.w)); \
        if(J==0) vr = b; \
        float wq_=wqp[rQ+s_], wk_=wkp[rQ+s_]; \
        aq0 += wq_*b.x; aq1 += wq_*b.y; aq2 += wq_*b.z; aq3 += wq_*b.w; \
        ak0 += wk_*b.x; ak1 += wk_*b.y; ak2 += wk_*b.z; ak3 += wk_*b.w; }
        STEPB(0)  STEPB(1)  STEPB(2)  STEPB(3)
        STEPB(4)  STEPB(5)  STEPB(6)  STEPB(7)
        STEPB(8)  STEPB(9)  STEPB(10) STEPB(11)
        STEPB(12) STEPB(13) STEPB(14) STEPB(15)
#undef STEPB
    }

    // --- A epilogue: scale + store to qv/kv ---
    {
        float sq_ = scQ[r], sk_ = scK[r];
        float q0 = clampf(sq_*aq0,1e18f), q1=clampf(sq_*aq1,1e18f),
              q2 = clampf(sq_*aq2,1e18f), q3=clampf(sq_*aq3,1e18f);
        float k0 = clampf(sk_*ak0,1e18f), k1=clampf(sk_*ak1,1e18f),
              k2 = clampf(sk_*ak2,1e18f), k3=clampf(sk_*ak3,1e18f);
        if(i0==0 && tid==0){ q0 = chQ[r]; k0 = chK[r]; }
        *(float4*)(qv + row*QS + l*4) = make_float4(q0,q1,q2,q3);
        *(float4*)(kv + row*QS + l*4) = make_float4(k0,k1,k2,k3);
    }

    // --- C1: v row = vr (pure register) ---
    {
        *(float4*)(vrow + row*VS + l*4) = vr;
        float x0v = vrow[row*VS];
        float inv0 = __fdividef(1.f, ((fabsf(x0v)>1e-20f)? x0v : 1e-20f));
        float sv = 0.f;
#pragma unroll
        for(int m=0;m<4;m++){
            int kp = l + 16*m;
            if(kp < 63){ float vi = vrow[row*VS + 1 + kp]*inv0; sv += vi*vi; }
        }
        sv = red16(sv);
        if(l==0){ lamb[row] = rsqrtf(1.f - fminf(sv, 0.9f)); invv[row] = inv0; }
        if(tid<16) ssum[tid]=0.f;
        Cm[tid]=0.f;
        if(tid<16) Cm[256+tid]=0.f;
    }

    // --- M: mobius_add(+proj) on q and k rows, in-wave ---
    {
        float xq[4], xk[4];
        float syq=0,suq=0,syk=0,suk=0;
#pragma unroll
        for(int m=0;m<4;m++){
            int k = l+16*m;
            xq[m]=qv[row*QS+k]; xk[m]=kv[row*QS+k];
            if(k>0){ syq+=xq[m]*xq[m]; suq+=xq[m]*uq[k];
                     syk+=xk[m]*xk[m]; suk+=xk[m]*uk[k]; }
        }
        syq=red16(syq); suq=red16(suq); syk=red16(syk); suk=red16(suk);
        float x0q=qv[row*QS], x0k=kv[row*QS];
        float xnq=fmaxf(sqrtf(fmaxf(syq,0.f)),MINN);
        float xnk=fmaxf(sqrtf(fmaxf(syk,0.f)),MINN);
        float alq=clampf(__fdividef(suq, xnq*sqK),1e12f);
        float alk=clampf(__fdividef(suk, xnk*sqK),1e12f);
        float cfq=clampf(__fdividef(alq*(sqK-x0q), xnq),1e12f);
        float cfk=clampf(__fdividef(alk*(sqK-x0k), xnk),1e12f);
        float wq4[4], wk4[4];
        float uxq=0,swq=0,uxk=0,swk=0;
#pragma unroll
        for(int m=0;m<4;m++){
            int k=l+16*m;
            if(k>0){
                wq4[m]=clampf(uq[k]-cfq*xq[m],1e15f); uxq+=xq[m]*wq4[m]; swq+=wq4[m]*wq4[m];
                wk4[m]=clampf(uk[k]-cfk*xk[m],1e15f); uxk+=xk[m]*wk4[m]; swk+=wk4[m]*wk4[m];
            } else { wq4[m]=0.f; wk4[m]=0.f; }
        }
        uxq=red16(uxq); swq=red16(swq); uxk=red16(uxk); swk=red16(swk);
        float V0q=__fdividef(uxq, fmaxf(x0q,EPSF));
        float V0k=__fdividef(uxk, fmaxf(x0k,EPSF));
        float mnq=sqrtf(fmaxf(swq-V0q*V0q,EPSF));
        float mnk=sqrtf(fmaxf(swk-V0k*V0k,EPSF));
        float thq=fminf(fmaxf(fminf(mnq,1e6f)/sqK,MINN),20.f);
        float thk=fminf(fmaxf(fminf(mnk,1e6f)/sqK,MINN),20.f);
        float chq=coshf(thq), stq=__fdividef(sinhf(thq), thq);
        float chk=coshf(thk), stk=__fdividef(sinhf(thk), thk);
        float zq4[4], zk4[4];
        float szq=0,szk=0;
#pragma unroll
        for(int m=0;m<4;m++){
            int k=l+16*m;
            if(k>0){
                zq4[m]=clampf(chq*xq[m]+stq*wq4[m],1e15f); szq+=zq4[m]*zq4[m];
                zk4[m]=clampf(chk*xk[m]+stk*wk4[m],1e15f); szk+=zk4[m]*zk4[m];
            } else { zq4[m]=0.f; zk4[m]=0.f; }
        }
        szq=red16(szq); szk=red16(szk);
        float fq = sqrtf(fmaxf(K+szq,EPSF));
        float fk = sqrtf(fmaxf(K+szk,EPSF));
#pragma unroll
        for(int m=0;m<4;m++){
            int k=l+16*m;
            qv[row*QS+k] = (k==0)? fq : zq4[m];
            kv[row*QS+k] = (k==0)? fk : zk4[m];
        }
    }
    __syncthreads();

    // --- C2: scores; scatter s_sum ---
    if(tid<NE){
        int m = tmv[tid], nn = tnv[tid];
        const float4* qp = (const float4*)(qv + m*QS);
        const float4* kp = (const float4*)(kv + nn*QS);
        float dot = 0.f;
#pragma unroll
        for(int t4=0;t4<16;t4++){
            float4 q4 = qp[t4], k4 = kp[t4];
            dot += q4.x*k4.x + q4.y*k4.y + q4.z*k4.z + q4.w*k4.w;
        }
        float mdot = dot - 2.f*qv[m*QS]*kv[nn*QS];
        float th = fmaxf(-mdot*cv, 1.0f+EPSF);
        float ac = __logf(th + sqrtf(fmaxf(th*th - 1.0f, EPSF)));
        float sqd = fminf(K*ac*ac, 50.f);
        float sval = __expf(fminf(-av*sqd - cv + maskv[tid], 80.f));
        Cm[m*CMS+nn] = sval;
        atomicAdd(&ssum[m], sval);
    }
    __syncthreads();

    // --- C3: scale ---
    if(tid<NE){
        int m = tmv[tid], nn = tnv[tid];
        Cm[m*CMS+nn] = __fdividef(lamb[nn]*Cm[m*CMS+nn], fmaxf(ssum[nn],1e-37f));
    }
    __syncthreads();

    // --- D: weighted Klein average + k2h ---
    {
        float cs[16]; float wsm = 0.f;
#pragma unroll
        for(int s=0;s<16;s++){
            float cmv = Cm[row*CMS+s];
            wsm += cmv;
            cs[s] = cmv*invv[s];
        }
        wsm = fmaxf(wsm, 1e-37f);
        float iwsm = __fdividef(1.f, wsm);
        float g4[4]; float sg=0.f;
#pragma unroll
        for(int m=0;m<4;m++){
            int kp = l+16*m;
            float num = 0.f;
#pragma unroll
            for(int s=0;s<16;s++) num += cs[s]*vrow[s*VS + 1 + kp];
            float gvv = (kp<63)? num*iwsm : 0.f;
            g4[m]=gvv; sg += gvv*gvv;
        }
        sg = red16(sg);
        float inv = rsqrtf(1.f - fminf(sg, 0.999f));
        size_t base = ((size_t)(512*r + i0)*16 + row)*64;
        if(l==0) out[base] = inv;
#pragma unroll
        for(int m=0;m<4;m++){
            int kp=l+16*m;
            if(kp<63) out[base+1+kp] = g4[m]*inv;
        }
    }
}

extern "C" void kernel_launch(void* const* d_in, const int* in_sizes, int n_in,
                              void* d_out, int out_size, void* d_ws, size_t ws_size,
                              hipStream_t stream){
    const void* H    = d_in[0];
    const int* tidx  = (const int*)d_in[1];
    const void* mask = d_in[2];
    const void* wq   = d_in[3];
    const void* wk   = d_in[4];
    const void* bq   = d_in[5];
    const void* bk   = d_in[6];
    const void* aa   = d_in[7];
    const void* cc   = d_in[8];
    float* out = (float*)d_out;
    float* ws  = (float*)d_ws;

    hipMemsetAsync(ws, 0, NBANK*NE*sizeof(float), stream);
    gram4_k<<<512, 256,0,stream>>>(H, ws);
    fin4_k <<<1,   256,0,stream>>>(H, wq, wk, bq, bk, cc, ws);
    main9_k<<<8192,256,0,stream>>>(H, tidx, mask, aa, cc, ws, out);
}